// Round 10
// baseline (235.248 us; speedup 1.0000x reference)
//
#include <hip/hip_runtime.h>

typedef short short8 __attribute__((ext_vector_type(8)));
typedef float f32x4  __attribute__((ext_vector_type(4)));

// Problem dims
constexpr int N_    = 256;
constexpr int T_    = 2048;
constexpr int V_    = 9;
constexpr int FIN_  = 144;      // K dim of stage-1 GEMM
constexpr int J_    = 27;       // output cols (w*3 + o)
constexpr int KT_   = 9;
constexpr int THREADS_ = 256;   // 4 waves
constexpr int TILE_  = 248;     // output rows per block
constexpr int NTILE_ = 9;
constexpr int NWG_   = N_ * NTILE_;   // 2304 = 8 * 288 (exact -> bijective XCD swizzle)
constexpr int PERXCD_ = NWG_ / 8;     // 288
constexpr int XSTRIDE_B = 336;              // bf16 row stride (84 words: 2-way banks = free)
constexpr int XBUF_B  = 64 * XSTRIDE_B;     // 21504 B (phase tile; also holds Wc 15552B at setup)
constexpr int ZROWS_  = 256;
constexpr int ZS_     = 28;                 // f32 stride 112B: b128 reads = conflict-free minimum
constexpr int SMEM_B  = XBUF_B + ZROWS_ * ZS_ * 4;   // 50176 B -> 3 blocks/CU

__device__ __forceinline__ unsigned short bf16_rne(float x) {
    unsigned u = __float_as_uint(x);
    u = (u + 0x7FFFu + ((u >> 16) & 1u)) >> 16;
    return (unsigned short)u;
}
__device__ __forceinline__ unsigned pk2(float a, float b) {
    return (unsigned)bf16_rne(a) | ((unsigned)bf16_rne(b) << 16);
}

__global__ __launch_bounds__(THREADS_, 3) void fused_stgcn(const float* __restrict__ pose,
                                                           const float* __restrict__ Ain,
                                                           const float* __restrict__ Wg,
                                                           const float* __restrict__ bg,
                                                           const float* __restrict__ Wt_in,
                                                           const float* __restrict__ bt,
                                                           float* __restrict__ out) {
    __shared__ __align__(16) unsigned char smem[SMEM_B];
    float* zbuf = (float*)(smem + XBUF_B);

    const int tid  = threadIdx.x;
    // XCD-bijective swizzle: HW round-robins blockIdx across 8 XCDs; this makes each XCD
    // process a CONTIGUOUS 288-tile chunk -> 8 sequential DRAM frontiers, L2-local.
    const int sbid = (blockIdx.x & 7) * PERXCD_ + (blockIdx.x >> 3);
    const int nb   = sbid / NTILE_;
    const int tile = sbid % NTILE_;
    const int t0   = tile * TILE_;
    const int lane = tid & 63;
    const int wv   = tid >> 6;
    const int g8   = lane >> 4;
    const int j0   = lane & 15;
    const size_t nrow0 = (size_t)nb * T_;

    // LDS-only barrier: global loads stay in flight across it
    auto WB = []() {
        asm volatile("s_waitcnt lgkmcnt(0)" ::: "memory");
        __builtin_amdgcn_s_barrier();
        asm volatile("" ::: "memory");
    };

    auto issue = [&](int h, f32x4* ld) {
        #pragma unroll
        for (int q = 0; q < 9; ++q) {
            const int fidx = q * THREADS_ + tid;
            const int r = fidx / 36, c4 = fidx % 36;
            const int text = t0 - 4 + h * 64 + r;
            const bool ok = (text >= 0 && text < T_);
            const f32x4* p = (const f32x4*)(pose + (nrow0 + (size_t)(ok ? text : 0)) * FIN_ + c4 * 4);
            const f32x4 v = __builtin_nontemporal_load(p);   // streaming: don't pollute L3
            ld[q] = ok ? v : (f32x4){0.f, 0.f, 0.f, 0.f};
        }
    };
    auto stage = [&](const f32x4* ld) {
        #pragma unroll
        for (int q = 0; q < 9; ++q) {
            const int fidx = q * THREADS_ + tid;
            const int r = fidx / 36, c4 = fidx % 36;
            uint2 u;
            u.x = pk2(ld[q][0], ld[q][1]);
            u.y = pk2(ld[q][2], ld[q][3]);
            *(uint2*)(smem + r * XSTRIDE_B + c4 * 8) = u;
        }
    };

    f32x4 lda[9], ldb[9];
    issue(0, lda);                         // first tile's loads overlap the setup compute below

    // ---- Inline setup: Wc[f=(v,c)][j=(w,o)] into LDS (x-region), then B-frags ----
    float* wc = (float*)smem;
    for (int idx = tid; idx < FIN_ * J_; idx += THREADS_) {
        const int f = idx / J_, j = idx % J_;
        const int v = f >> 4, c = f & 15;
        const int w = j / 3, o = j % 3;
        float s = 0.f;
        #pragma unroll
        for (int k = 0; k < 5; ++k)
            s += Wg[(k * 3 + o) * 16 + c] * Ain[(k * 9 + v) * 9 + w];
        wc[idx] = s;
    }
    // per-lane GCN bias B0[n] = sum_k bg[k,o] * sum_v A[k,v,w], n = w*3+o
    float b0n0, b0n1 = 0.f;
    {
        const int n0 = j0, w0 = n0 / 3, o0 = n0 % 3;
        float s0 = 0.f;
        #pragma unroll
        for (int k = 0; k < 5; ++k) {
            float cs = 0.f;
            #pragma unroll
            for (int v = 0; v < V_; ++v) cs += Ain[(k * 9 + v) * 9 + w0];
            s0 += bg[k * 3 + o0] * cs;
        }
        b0n0 = s0;
        if (j0 < 11) {
            const int n1 = 16 + j0, w1 = n1 / 3, o1 = n1 % 3;
            float s1 = 0.f;
            #pragma unroll
            for (int k = 0; k < 5; ++k) {
                float cs = 0.f;
                #pragma unroll
                for (int v = 0; v < V_; ++v) cs += Ain[(k * 9 + v) * 9 + w1];
                s1 += bg[k * 3 + o1] * cs;
            }
            b0n1 = s1;
        }
    }
    WB();   // Wc visible
    // B-frags (16x16x32 bf16): elem e of lane = Wc[k=s*32+g8*8+e][n=nt*16+j0]
    short8 bfrag[5][2];
    #pragma unroll
    for (int s = 0; s < 5; ++s) {
        #pragma unroll
        for (int nt = 0; nt < 2; ++nt) {
            const int n = nt * 16 + j0;
            union { unsigned u[4]; short8 s8; } cvu;
            #pragma unroll
            for (int ep = 0; ep < 4; ++ep) {
                const int k0 = s * 32 + g8 * 8 + ep * 2;
                const float v0 = (k0 < FIN_ && n < J_)     ? wc[k0 * J_ + n]       : 0.f;
                const float v1 = (k0 + 1 < FIN_ && n < J_) ? wc[(k0 + 1) * J_ + n] : 0.f;
                cvu.u[ep] = pk2(v0, v1);
            }
            bfrag[s][nt] = cvu.s8;
        }
    }
    WB();   // Wc reads done; x-region free for staging
    // zero k-pad bytes [288,320) of each staged row (s=4 frag tail reads them)
    for (int i = tid; i < 512; i += THREADS_) {
        const int r = i >> 3, w = i & 7;
        *(float*)(smem + r * XSTRIDE_B + 288 + w * 4) = 0.f;
    }
    issue(1, ldb);                         // second phase in flight before the loop

    // ---- Stage 1: 4 phases x 64 rows; wave wv owns rows [wv*16, wv*16+16) ----
    #pragma unroll 1
    for (int h = 0; h < 4; ++h) {
        f32x4* cur = (h & 1) ? ldb : lda;
        stage(cur);                        // waits this phase's vmcnt; buffer now dead
        if (h < 2) issue(h + 2, cur);      // refill: ~2 phases of flight time
        WB();                              // staged tile (and pad zeros on h==0) visible

        const unsigned char* abase = smem + (wv * 16 + j0) * XSTRIDE_B;
        f32x4 acc0 = {0.f, 0.f, 0.f, 0.f};
        f32x4 acc1 = {0.f, 0.f, 0.f, 0.f};
        #pragma unroll
        for (int s = 0; s < 5; ++s) {
            const short8 af = *(const short8*)(abase + s * 64 + g8 * 16);
            acc0 = __builtin_amdgcn_mfma_f32_16x16x32_bf16(af, bfrag[s][0], acc0, 0, 0, 0);
            acc1 = __builtin_amdgcn_mfma_f32_16x16x32_bf16(af, bfrag[s][1], acc1, 0, 0, 0);
        }
        // D layout: col = lane&15, row = g8*4 + reg
        #pragma unroll
        for (int r = 0; r < 4; ++r) {
            const int zrow = h * 64 + wv * 16 + g8 * 4 + r;
            const int text = t0 - 4 + zrow;
            const bool okz = (text >= 0 && text < T_);
            zbuf[zrow * ZS_ + j0] = okz ? acc0[r] + b0n0 : 0.f;
            if (j0 < 11)
                zbuf[zrow * ZS_ + 16 + j0] = okz ? acc1[r] + b0n1 : 0.f;
        }
        WB();                              // frag reads + z writes done before next stage()
    }

    // ---- Stage 2: temporal 9-tap mix + bias + leaky relu ----
    const int rows_out = min(TILE_, T_ - t0);
    float oacc[J_];
    if (tid < rows_out) {
        #pragma unroll
        for (int w = 0; w < V_; ++w)
            #pragma unroll
            for (int o2 = 0; o2 < 3; ++o2)
                oacc[w * 3 + o2] = bt[o2];
        #pragma unroll
        for (int dd = 0; dd < KT_; ++dd) {
            union { f32x4 v4[7]; float f[28]; } zu;
            const f32x4* zp = (const f32x4*)&zbuf[(tid + dd) * ZS_];
            #pragma unroll
            for (int c = 0; c < 7; ++c) zu.v4[c] = zp[c];
            #pragma unroll
            for (int o = 0; o < 3; ++o) {
                #pragma unroll
                for (int o2 = 0; o2 < 3; ++o2) {
                    const float wt = Wt_in[(o2 * 3 + o) * KT_ + (KT_ - 1 - dd)];
                    #pragma unroll
                    for (int w = 0; w < V_; ++w)
                        oacc[w * 3 + o2] = fmaf(zu.f[w * 3 + o], wt, oacc[w * 3 + o2]);
                }
            }
        }
        #pragma unroll
        for (int j = 0; j < J_; ++j) oacc[j] = fmaxf(oacc[j], 0.01f * oacc[j]);
    }
    WB();   // stage-2 reads of zbuf complete
    // repack tight f32 (stride 27) into smem base for coalesced store
    float* rp = (float*)smem;
    if (tid < rows_out) {
        #pragma unroll
        for (int j = 0; j < J_; ++j) rp[tid * J_ + j] = oacc[j];
    }
    WB();   // repack visible

    const int total4 = (rows_out * J_) / 4;   // 1674 or 432
    f32x4* dst4 = (f32x4*)(out + (nrow0 + t0) * J_);
    const f32x4* src4 = (const f32x4*)rp;
    for (int idx = tid; idx < total4; idx += THREADS_)
        __builtin_nontemporal_store(src4[idx], &dst4[idx]);   // no-reuse output
}

extern "C" void kernel_launch(void* const* d_in, const int* in_sizes, int n_in,
                              void* d_out, int out_size, void* d_ws, size_t ws_size,
                              hipStream_t stream) {
    const float* pose = (const float*)d_in[0];
    const float* A    = (const float*)d_in[1];
    const float* Wg   = (const float*)d_in[2];
    const float* bg   = (const float*)d_in[3];
    const float* Wt   = (const float*)d_in[4];
    const float* bt   = (const float*)d_in[5];
    float* outp = (float*)d_out;

    fused_stgcn<<<NWG_, THREADS_, 0, stream>>>(pose, A, Wg, bg, Wt, bt, outp);
}

// Round 11
// 87.472 us; speedup vs baseline: 2.6894x; 2.6894x over previous
//
#include <hip/hip_runtime.h>

typedef short short8 __attribute__((ext_vector_type(8)));
typedef float f32x4  __attribute__((ext_vector_type(4)));

// Problem dims
constexpr int N_    = 256;
constexpr int T_    = 2048;
constexpr int V_    = 9;
constexpr int FIN_  = 144;      // K dim of stage-1 GEMM
constexpr int J_    = 27;       // output cols (w*3 + o)
constexpr int KT_   = 9;
constexpr int THREADS_ = 256;   // 4 waves
constexpr int TILE_  = 248;     // output rows per block
constexpr int NTILE_ = 9;
constexpr int XSTRIDE_B = 336;              // bf16 row stride (84 words: 2-way banks = free)
constexpr int XBUF_B  = 64 * XSTRIDE_B;     // 21504 B (one 64-row phase tile)
constexpr int ZROWS_  = 256;
constexpr int ZS_     = 28;                 // 112B; b128 reads -> 8/bank uniform = conflict-free min
constexpr int SMEM_B  = XBUF_B + ZROWS_ * ZS_ * 4;   // 50176 B -> 3 blocks/CU

// ws layout (float units)
constexpr int BF_OFF_F = 0;      // B-frags: 5120 bf16 (2560 floats)
constexpr int B0_OFF   = 2560;   // B0[27]
constexpr int WT_OFF   = 2587;   // Wt[o][o2][dd] (81)
constexpr int BT_OFF   = 2668;   // b_tcn[3]

__device__ __forceinline__ unsigned short bf16_rne(float x) {
    unsigned u = __float_as_uint(x);
    u = (u + 0x7FFFu + ((u >> 16) & 1u)) >> 16;
    return (unsigned short)u;
}
__device__ __forceinline__ unsigned pk2(float a, float b) {
    return (unsigned)bf16_rne(a) | ((unsigned)bf16_rne(b) << 16);
}

__global__ void setup_weights(const float* __restrict__ A,
                              const float* __restrict__ Wg,
                              const float* __restrict__ bg,
                              const float* __restrict__ Wt_in,
                              const float* __restrict__ bt,
                              float* __restrict__ ws) {
    __shared__ float Wc[FIN_ * J_];   // [k=f][n=j]
    const int tid = threadIdx.x;
    for (int idx = tid; idx < FIN_ * J_; idx += 256) {
        const int f = idx / J_, j = idx % J_;
        const int v = f >> 4, c = f & 15;
        const int w = j / 3, o = j % 3;
        float s = 0.f;
        #pragma unroll
        for (int k = 0; k < 5; ++k)
            s += Wg[(k * 3 + o) * 16 + c] * A[(k * 9 + v) * 9 + w];
        Wc[idx] = s;
    }
    __syncthreads();
    // B-fragments for mfma_f32_16x16x32_bf16: elem e of lane: (k=s*32+(l>>4)*8+e, n=nt*16+(l&15))
    unsigned short* bfp = (unsigned short*)(ws + BF_OFF_F);
    for (int i = tid; i < 5120; i += 256) {
        const int e = i & 7, lane = (i >> 3) & 63, nt = (i >> 9) & 1, s = i >> 10;
        const int k = s * 32 + (lane >> 4) * 8 + e;
        const int n = nt * 16 + (lane & 15);
        const float val = (k < FIN_ && n < J_) ? Wc[k * J_ + n] : 0.f;
        bfp[i] = bf16_rne(val);
    }
    if (tid < J_) {
        const int w = tid / 3, o = tid % 3;
        float s = 0.f;
        #pragma unroll
        for (int k = 0; k < 5; ++k) {
            float cs = 0.f;
            #pragma unroll
            for (int v = 0; v < V_; ++v) cs += A[(k * 9 + v) * 9 + w];
            s += bg[k * 3 + o] * cs;
        }
        ws[B0_OFF + tid] = s;
    }
    // Wt[o][o2][dd] = W_tcn[(o2*3+o)*9 + (8-dd)]  (conv_transpose: flip + I/O swap)
    if (tid < 81) {
        const int o = tid / 27, r = tid % 27, o2 = r / 9, dd = r % 9;
        ws[WT_OFF + tid] = Wt_in[(o2 * 3 + o) * 9 + (8 - dd)];
    }
    if (tid < 3) ws[BT_OFF + tid] = bt[tid];
}

__global__ __launch_bounds__(THREADS_) void fused_stgcn(const float* __restrict__ pose,
                                                        const float* __restrict__ cw,
                                                        float* __restrict__ out) {
    __shared__ __align__(16) unsigned char smem[SMEM_B];
    float* zbuf = (float*)(smem + XBUF_B);

    const int tid  = threadIdx.x;
    const int bid  = blockIdx.x;
    const int nb   = bid / NTILE_;
    const int tile = bid % NTILE_;
    const int t0   = tile * TILE_;
    const int lane = tid & 63;
    const int wv   = tid >> 6;
    const int g8   = lane >> 4;
    const int j0   = lane & 15;
    const size_t nrow0 = (size_t)nb * T_;

    // LDS-only barrier: global loads stay in flight (vs __syncthreads's vmcnt(0) drain)
    auto WB = []() {
        asm volatile("s_waitcnt lgkmcnt(0)" ::: "memory");
        __builtin_amdgcn_s_barrier();
        asm volatile("" ::: "memory");
    };

    // issue phase-h loads: one CONTIGUOUS 36864B region, 9 coalesced float4/lane
    auto issue = [&](int h, float4* ld) {
        #pragma unroll
        for (int q = 0; q < 9; ++q) {
            const int fidx = q * THREADS_ + tid;
            const int r = fidx / 36, c4 = fidx % 36;
            const int text = t0 - 4 + h * 64 + r;
            const bool ok = (text >= 0 && text < T_);
            const float* p = pose + (nrow0 + (size_t)(ok ? text : 0)) * FIN_ + c4 * 4;
            ld[q] = ok ? *(const float4*)p : make_float4(0.f, 0.f, 0.f, 0.f);
        }
    };
    auto stage = [&](const float4* ld) {
        #pragma unroll
        for (int q = 0; q < 9; ++q) {
            const int fidx = q * THREADS_ + tid;
            const int r = fidx / 36, c4 = fidx % 36;
            uint2 u;
            u.x = pk2(ld[q].x, ld[q].y);
            u.y = pk2(ld[q].z, ld[q].w);
            *(uint2*)(smem + r * XSTRIDE_B + c4 * 8) = u;
        }
    };

    float4 lda[9], ldb[9];
    issue(0, lda);

    // k-pad bytes [288,320) of each staged row must be zero (s=4 frag tail); written once
    for (int i = tid; i < 512; i += THREADS_) {
        const int r = i >> 3, w = i & 7;
        *(float*)(smem + r * XSTRIDE_B + 288 + w * 4) = 0.f;
    }
    // B-fragments -> registers (40 VGPRs), L2-resident
    short8 bfrag[5][2];
    {
        const short8* bsrc = (const short8*)(cw + BF_OFF_F);
        #pragma unroll
        for (int s = 0; s < 5; ++s)
            #pragma unroll
            for (int nt = 0; nt < 2; ++nt)
                bfrag[s][nt] = bsrc[(s * 2 + nt) * 64 + lane];
    }
    const float b0n0 = cw[B0_OFF + j0];
    const float b0n1 = (j0 < 11) ? cw[B0_OFF + 16 + j0] : 0.f;

    // ---- Stage 1: 4 phases; wave wv owns rows [wv*16, wv*16+16) of each 64-row phase ----
    #pragma unroll
    for (int h = 0; h < 4; ++h) {
        float4* cur = (h & 1) ? ldb : lda;
        float4* nxt = (h & 1) ? lda : ldb;
        if (h < 3) issue(h + 1, nxt);     // next phase's 36KB in flight before this phase's stall
        stage(cur);
        WB();                              // staged tile visible

        const unsigned char* abase = smem + (wv * 16 + j0) * XSTRIDE_B;
        f32x4 acc0 = {0.f, 0.f, 0.f, 0.f};
        f32x4 acc1 = {0.f, 0.f, 0.f, 0.f};
        #pragma unroll
        for (int s = 0; s < 5; ++s) {
            const short8 af = *(const short8*)(abase + s * 64 + g8 * 16);
            acc0 = __builtin_amdgcn_mfma_f32_16x16x32_bf16(af, bfrag[s][0], acc0, 0, 0, 0);
            acc1 = __builtin_amdgcn_mfma_f32_16x16x32_bf16(af, bfrag[s][1], acc1, 0, 0, 0);
        }
        // D layout: col = lane&15, row = (lane>>4)*4 + reg
        #pragma unroll
        for (int r = 0; r < 4; ++r) {
            const int zrow = h * 64 + wv * 16 + g8 * 4 + r;
            const int text = t0 - 4 + zrow;
            const bool okz = (text >= 0 && text < T_);
            zbuf[zrow * ZS_ + j0] = okz ? acc0[r] + b0n0 : 0.f;
            if (j0 < 11)
                zbuf[zrow * ZS_ + 16 + j0] = okz ? acc1[r] + b0n1 : 0.f;
        }
        WB();                              // frag reads + z writes done before next phase's stage()
    }

    // ---- Stage 2: temporal 9-tap mix + bias + leaky relu ----
    const int rows_out = min(TILE_, T_ - t0);
    float oacc[J_];
    if (tid < rows_out) {
        #pragma unroll
        for (int w = 0; w < V_; ++w)
            #pragma unroll
            for (int o2 = 0; o2 < 3; ++o2)
                oacc[w * 3 + o2] = cw[BT_OFF + o2];
        #pragma unroll
        for (int dd = 0; dd < KT_; ++dd) {
            union { f32x4 v4[7]; float f[28]; } zu;
            const f32x4* zp = (const f32x4*)&zbuf[(tid + dd) * ZS_];
            #pragma unroll
            for (int c = 0; c < 7; ++c) zu.v4[c] = zp[c];
            #pragma unroll
            for (int o = 0; o < 3; ++o) {
                #pragma unroll
                for (int o2 = 0; o2 < 3; ++o2) {
                    const float wt = cw[WT_OFF + o * 27 + o2 * 9 + dd];
                    #pragma unroll
                    for (int w = 0; w < V_; ++w)
                        oacc[w * 3 + o2] = fmaf(zu.f[w * 3 + o], wt, oacc[w * 3 + o2]);
                }
            }
        }
        #pragma unroll
        for (int j = 0; j < J_; ++j) oacc[j] = fmaxf(oacc[j], 0.01f * oacc[j]);
    }
    WB();   // stage-2 reads complete
    if (tid < rows_out) {
        #pragma unroll
        for (int j = 0; j < J_; ++j) zbuf[tid * J_ + j] = oacc[j];
    }
    WB();   // repack visible

    const int total4 = (rows_out * J_) / 4;   // 1674 or 432
    float4* dst4 = (float4*)(out + (nrow0 + t0) * J_);
    const float4* src4 = (const float4*)zbuf;
    for (int idx = tid; idx < total4; idx += THREADS_)
        dst4[idx] = src4[idx];
}

extern "C" void kernel_launch(void* const* d_in, const int* in_sizes, int n_in,
                              void* d_out, int out_size, void* d_ws, size_t ws_size,
                              hipStream_t stream) {
    const float* pose = (const float*)d_in[0];
    const float* A    = (const float*)d_in[1];
    const float* Wg   = (const float*)d_in[2];
    const float* bg   = (const float*)d_in[3];
    const float* Wt   = (const float*)d_in[4];
    const float* bt   = (const float*)d_in[5];
    float* ws   = (float*)d_ws;
    float* outp = (float*)d_out;

    setup_weights<<<1, 256, 0, stream>>>(A, Wg, bg, Wt, bt, ws);
    fused_stgcn<<<N_ * NTILE_, THREADS_, 0, stream>>>(pose, ws, outp);
}

// Round 12
// 87.443 us; speedup vs baseline: 2.6903x; 1.0003x over previous
//
#include <hip/hip_runtime.h>

typedef short short8 __attribute__((ext_vector_type(8)));
typedef float f32x4  __attribute__((ext_vector_type(4)));

// Problem dims
constexpr int N_    = 256;
constexpr int T_    = 2048;
constexpr int V_    = 9;
constexpr int FIN_  = 144;      // K dim of stage-1 GEMM
constexpr int J_    = 27;       // output cols (w*3 + o)
constexpr int KT_   = 9;
constexpr int THREADS_ = 256;   // 4 waves
constexpr int TILE_  = 248;     // output rows per block
constexpr int NTILE_ = 9;
constexpr int XSTRIDE_B = 336;              // bf16 row stride (84 words: 2-way banks = free)
constexpr int XBUF_B  = 64 * XSTRIDE_B;     // 21504 B (one 64-row phase tile)
constexpr int ZROWS_  = 256;
constexpr int ZS_     = 28;                 // 112B; b128 reads -> 8/bank uniform = conflict-free min
constexpr int SMEM_B  = XBUF_B + ZROWS_ * ZS_ * 4;   // 50176 B -> 3 blocks/CU

// ws layout (float units)
constexpr int BF_OFF_F = 0;      // B-frags: 5120 bf16 (2560 floats)
constexpr int B0_OFF   = 2560;   // B0[27]
constexpr int WT_OFF   = 2587;   // Wt[o][o2][dd] (81)
constexpr int BT_OFF   = 2668;   // b_tcn[3]

__device__ __forceinline__ unsigned short bf16_rne(float x) {
    unsigned u = __float_as_uint(x);
    u = (u + 0x7FFFu + ((u >> 16) & 1u)) >> 16;
    return (unsigned short)u;
}
__device__ __forceinline__ unsigned pk2(float a, float b) {
    return (unsigned)bf16_rne(a) | ((unsigned)bf16_rne(b) << 16);
}

__global__ void setup_weights(const float* __restrict__ A,
                              const float* __restrict__ Wg,
                              const float* __restrict__ bg,
                              const float* __restrict__ Wt_in,
                              const float* __restrict__ bt,
                              float* __restrict__ ws) {
    __shared__ float Wc[FIN_ * J_];   // [k=f][n=j]
    const int tid = threadIdx.x;
    for (int idx = tid; idx < FIN_ * J_; idx += 256) {
        const int f = idx / J_, j = idx % J_;
        const int v = f >> 4, c = f & 15;
        const int w = j / 3, o = j % 3;
        float s = 0.f;
        #pragma unroll
        for (int k = 0; k < 5; ++k)
            s += Wg[(k * 3 + o) * 16 + c] * A[(k * 9 + v) * 9 + w];
        Wc[idx] = s;
    }
    __syncthreads();
    // B-fragments for mfma_f32_16x16x32_bf16: elem e of lane: (k=s*32+(l>>4)*8+e, n=nt*16+(l&15))
    unsigned short* bfp = (unsigned short*)(ws + BF_OFF_F);
    for (int i = tid; i < 5120; i += 256) {
        const int e = i & 7, lane = (i >> 3) & 63, nt = (i >> 9) & 1, s = i >> 10;
        const int k = s * 32 + (lane >> 4) * 8 + e;
        const int n = nt * 16 + (lane & 15);
        const float val = (k < FIN_ && n < J_) ? Wc[k * J_ + n] : 0.f;
        bfp[i] = bf16_rne(val);
    }
    if (tid < J_) {
        const int w = tid / 3, o = tid % 3;
        float s = 0.f;
        #pragma unroll
        for (int k = 0; k < 5; ++k) {
            float cs = 0.f;
            #pragma unroll
            for (int v = 0; v < V_; ++v) cs += A[(k * 9 + v) * 9 + w];
            s += bg[k * 3 + o] * cs;
        }
        ws[B0_OFF + tid] = s;
    }
    // Wt[o][o2][dd] = W_tcn[(o2*3+o)*9 + (8-dd)]  (conv_transpose: flip + I/O swap)
    if (tid < 81) {
        const int o = tid / 27, r = tid % 27, o2 = r / 9, dd = r % 9;
        ws[WT_OFF + tid] = Wt_in[(o2 * 3 + o) * 9 + (8 - dd)];
    }
    if (tid < 3) ws[BT_OFF + tid] = bt[tid];
}

__global__ __launch_bounds__(THREADS_) void fused_stgcn(const float* __restrict__ pose,
                                                        const float* __restrict__ cw,
                                                        float* __restrict__ out) {
    __shared__ __align__(16) unsigned char smem[SMEM_B];
    float* zbuf = (float*)(smem + XBUF_B);

    const int tid  = threadIdx.x;
    const int bid  = blockIdx.x;
    const int nb   = bid / NTILE_;
    const int tile = bid % NTILE_;
    const int t0   = tile * TILE_;
    const int lane = tid & 63;
    const int wv   = tid >> 6;
    const int g8   = lane >> 4;
    const int j0   = lane & 15;
    const size_t nrow0 = (size_t)nb * T_;

    // LDS-only barrier: global loads stay in flight (vs __syncthreads's vmcnt(0) drain)
    auto WB = []() {
        asm volatile("s_waitcnt lgkmcnt(0)" ::: "memory");
        __builtin_amdgcn_s_barrier();
        asm volatile("" ::: "memory");
    };

    // issue phase-h loads: contiguous 36864B region, 9 coalesced nt-float4/lane (L1-bypass stream)
    auto issue = [&](int h, f32x4* ld) {
        #pragma unroll
        for (int q = 0; q < 9; ++q) {
            const int fidx = q * THREADS_ + tid;
            const int r = fidx / 36, c4 = fidx % 36;
            const int text = t0 - 4 + h * 64 + r;
            const bool ok = (text >= 0 && text < T_);
            const f32x4* p = (const f32x4*)(pose + (nrow0 + (size_t)(ok ? text : 0)) * FIN_ + c4 * 4);
            const f32x4 v = __builtin_nontemporal_load(p);
            ld[q] = ok ? v : (f32x4){0.f, 0.f, 0.f, 0.f};
        }
    };
    auto stage = [&](const f32x4* ld) {
        #pragma unroll
        for (int q = 0; q < 9; ++q) {
            const int fidx = q * THREADS_ + tid;
            const int r = fidx / 36, c4 = fidx % 36;
            uint2 u;
            u.x = pk2(ld[q][0], ld[q][1]);
            u.y = pk2(ld[q][2], ld[q][3]);
            *(uint2*)(smem + r * XSTRIDE_B + c4 * 8) = u;
        }
    };

    f32x4 lda[9], ldb[9];
    issue(0, lda);

    // k-pad bytes [288,320) of each staged row must be zero (s=4 frag tail); written once
    for (int i = tid; i < 512; i += THREADS_) {
        const int r = i >> 3, w = i & 7;
        *(float*)(smem + r * XSTRIDE_B + 288 + w * 4) = 0.f;
    }
    // B-fragments -> registers (40 VGPRs), L2-resident
    short8 bfrag[5][2];
    {
        const short8* bsrc = (const short8*)(cw + BF_OFF_F);
        #pragma unroll
        for (int s = 0; s < 5; ++s)
            #pragma unroll
            for (int nt = 0; nt < 2; ++nt)
                bfrag[s][nt] = bsrc[(s * 2 + nt) * 64 + lane];
    }
    const float b0n0 = cw[B0_OFF + j0];
    const float b0n1 = (j0 < 11) ? cw[B0_OFF + 16 + j0] : 0.f;

    // ---- Stage 1: 4 phases; wave wv owns rows [wv*16, wv*16+16) of each 64-row phase ----
    #pragma unroll
    for (int h = 0; h < 4; ++h) {
        f32x4* cur = (h & 1) ? ldb : lda;
        f32x4* nxt = (h & 1) ? lda : ldb;
        if (h < 3) issue(h + 1, nxt);     // next phase's 36KB in flight before this phase's stall
        stage(cur);
        WB();                              // staged tile visible

        const unsigned char* abase = smem + (wv * 16 + j0) * XSTRIDE_B;
        f32x4 acc0 = {0.f, 0.f, 0.f, 0.f};
        f32x4 acc1 = {0.f, 0.f, 0.f, 0.f};
        #pragma unroll
        for (int s = 0; s < 5; ++s) {
            const short8 af = *(const short8*)(abase + s * 64 + g8 * 16);
            acc0 = __builtin_amdgcn_mfma_f32_16x16x32_bf16(af, bfrag[s][0], acc0, 0, 0, 0);
            acc1 = __builtin_amdgcn_mfma_f32_16x16x32_bf16(af, bfrag[s][1], acc1, 0, 0, 0);
        }
        // D layout: col = lane&15, row = (lane>>4)*4 + reg
        #pragma unroll
        for (int r = 0; r < 4; ++r) {
            const int zrow = h * 64 + wv * 16 + g8 * 4 + r;
            const int text = t0 - 4 + zrow;
            const bool okz = (text >= 0 && text < T_);
            zbuf[zrow * ZS_ + j0] = okz ? acc0[r] + b0n0 : 0.f;
            if (j0 < 11)
                zbuf[zrow * ZS_ + 16 + j0] = okz ? acc1[r] + b0n1 : 0.f;
        }
        WB();                              // frag reads + z writes done before next phase's stage()
    }

    // ---- Stage 2: temporal 9-tap mix + bias + leaky relu ----
    const int rows_out = min(TILE_, T_ - t0);
    float oacc[J_];
    if (tid < rows_out) {
        #pragma unroll
        for (int w = 0; w < V_; ++w)
            #pragma unroll
            for (int o2 = 0; o2 < 3; ++o2)
                oacc[w * 3 + o2] = cw[BT_OFF + o2];
        #pragma unroll
        for (int dd = 0; dd < KT_; ++dd) {
            union { f32x4 v4[7]; float f[28]; } zu;
            const f32x4* zp = (const f32x4*)&zbuf[(tid + dd) * ZS_];
            #pragma unroll
            for (int c = 0; c < 7; ++c) zu.v4[c] = zp[c];
            #pragma unroll
            for (int o = 0; o < 3; ++o) {
                #pragma unroll
                for (int o2 = 0; o2 < 3; ++o2) {
                    const float wt = cw[WT_OFF + o * 27 + o2 * 9 + dd];
                    #pragma unroll
                    for (int w = 0; w < V_; ++w)
                        oacc[w * 3 + o2] = fmaf(zu.f[w * 3 + o], wt, oacc[w * 3 + o2]);
                }
            }
        }
        #pragma unroll
        for (int j = 0; j < J_; ++j) oacc[j] = fmaxf(oacc[j], 0.01f * oacc[j]);
    }
    WB();   // stage-2 reads complete
    if (tid < rows_out) {
        #pragma unroll
        for (int j = 0; j < J_; ++j) zbuf[tid * J_ + j] = oacc[j];
    }
    WB();   // repack visible

    const int total4 = (rows_out * J_) / 4;   // 1674 or 432
    f32x4* dst4 = (f32x4*)(out + (nrow0 + t0) * J_);
    const f32x4* src4 = (const f32x4*)zbuf;
    for (int idx = tid; idx < total4; idx += THREADS_)
        __builtin_nontemporal_store(src4[idx], &dst4[idx]);   // streaming output
}

extern "C" void kernel_launch(void* const* d_in, const int* in_sizes, int n_in,
                              void* d_out, int out_size, void* d_ws, size_t ws_size,
                              hipStream_t stream) {
    const float* pose = (const float*)d_in[0];
    const float* A    = (const float*)d_in[1];
    const float* Wg   = (const float*)d_in[2];
    const float* bg   = (const float*)d_in[3];
    const float* Wt   = (const float*)d_in[4];
    const float* bt   = (const float*)d_in[5];
    float* ws   = (float*)d_ws;
    float* outp = (float*)d_out;

    setup_weights<<<1, 256, 0, stream>>>(A, Wg, bg, Wt, bt, ws);
    fused_stgcn<<<N_ * NTILE_, THREADS_, 0, stream>>>(pose, ws, outp);
}